// Round 1
// baseline (319.353 us; speedup 1.0000x reference)
//
#include <hip/hip_runtime.h>
#include <hip/hip_bf16.h>

// SlotMamba: B=64, K=256, D_MODEL=512, D_INNER=512, D_STATE=16, D_CONV=4, DT_RANK=32
// NTOK = 16384. Inputs f32, output f32. All three GEMMs (in_proj, x_proj+dt_proj,
// out_proj) run as bf16 MFMA 16x16x32 with f32 accum.
// dt/xi/zs use T-layout: [(b*512+d)*256 + t].
//
// ws layout (MB = 2^20):                lifetime
//   xiT  [0,  32MB) f32 T-layout        gemm(in) -> xproj, scan
//   xlnb [32, 48MB) bf16 [t][d]         ln -> gemm(in); head reused as xpwb/dtwb (cvtw -> xproj);
//                                       whole region reused as yab: scan -> gemm(out)
//   zsT  [48, 64MB) bf16 T-layout       gemm(in) -> scan; head reused as WbO after scan
//   dtT/o[64, 96MB) f32                 head = WbI (cvtw -> gemm(in)); then dtT; then o [t][d]
//   Bc   [96, 97MB), Cc [97, 98MB)      xproj -> scan

#define NTOK 16384
#define DM   512

typedef __attribute__((ext_vector_type(8))) short bf16x8;
typedef __attribute__((ext_vector_type(4))) float f32x4;

__device__ __forceinline__ unsigned short f2bf(float f){
  unsigned int u = __float_as_uint(f);
  u = (u + 0x7fffu + ((u >> 16) & 1u)) >> 16;   // RNE
  return (unsigned short)u;
}
__device__ __forceinline__ float bfu(unsigned short p){ return __uint_as_float(((unsigned int)p) << 16); }
__device__ __forceinline__ unsigned int pk2(float a, float b){
  return (unsigned int)f2bf(a) | ((unsigned int)f2bf(b) << 16);
}
__device__ __forceinline__ float silu(float a){ return a / (1.f + __expf(-a)); }

// async 16B/lane global->LDS: lane l deposits at ldsbase + l*16 (wave-uniform base)
__device__ __forceinline__ void async_cp16(const unsigned short* g, unsigned short* l){
  __builtin_amdgcn_global_load_lds(
      (const __attribute__((address_space(1))) unsigned int*)g,
      (__attribute__((address_space(3))) unsigned int*)l, 16, 0, 0);
}

// ---------------- K0: f32 -> bf16 weight convert ----------------------------
__global__ __launch_bounds__(256) void k_cvtw(const float* __restrict__ W,
                                              unsigned short* __restrict__ Wb){
  int i = (blockIdx.x*256 + threadIdx.x)*8;
  float4 a = *(const float4*)(W+i);
  float4 b = *(const float4*)(W+i+4);
  uint4 st = { pk2(a.x,a.y), pk2(a.z,a.w), pk2(b.x,b.y), pk2(b.z,b.w) };
  *(uint4*)(Wb+i) = st;
}

// ---------------- K1: LayerNorm(slots) -> xlnb (bf16, [t][d]) ---------------
__global__ __launch_bounds__(64) void k_ln(const float* __restrict__ x,
                                           const float* __restrict__ g,
                                           const float* __restrict__ b,
                                           unsigned short* __restrict__ out){
  int tok  = blockIdx.x;
  int lane = threadIdx.x;
  const float* row = x + (size_t)tok*DM + lane*8;
  float4 r0 = *(const float4*)row;
  float4 r1 = *(const float4*)(row + 4);
  float v[8] = {r0.x,r0.y,r0.z,r0.w, r1.x,r1.y,r1.z,r1.w};
  float s = 0.f;
  #pragma unroll
  for (int i=0;i<8;i++) s += v[i];
  #pragma unroll
  for (int o=32;o;o>>=1) s += __shfl_xor(s, o, 64);
  float m = s * (1.0f/512.0f);
  float vs = 0.f;
  #pragma unroll
  for (int i=0;i<8;i++){ float d = v[i]-m; vs += d*d; }
  #pragma unroll
  for (int o=32;o;o>>=1) vs += __shfl_xor(vs, o, 64);
  float rs = rsqrtf(vs*(1.0f/512.0f) + 1e-5f);
  float4 g0 = *(const float4*)(g + lane*8);
  float4 g1 = *(const float4*)(g + lane*8 + 4);
  float4 b0 = *(const float4*)(b + lane*8);
  float4 b1 = *(const float4*)(b + lane*8 + 4);
  float gv[8] = {g0.x,g0.y,g0.z,g0.w, g1.x,g1.y,g1.z,g1.w};
  float bv[8] = {b0.x,b0.y,b0.z,b0.w, b1.x,b1.y,b1.z,b1.w};
  float o8[8];
  #pragma unroll
  for (int i=0;i<8;i++) o8[i] = (v[i]-m)*rs*gv[i] + bv[i];
  uint4 st = { pk2(o8[0],o8[1]), pk2(o8[2],o8[3]), pk2(o8[4],o8[5]), pk2(o8[6],o8[7]) };
  *(uint4*)(out + (size_t)tok*DM + lane*8) = st;
}

// ---------------- K2: 128x128-tile bf16-MFMA GEMM  C = A @ Wb^T -------------
__global__ __launch_bounds__(256) void k_gemm(const unsigned short* __restrict__ A,
                                              const unsigned short* __restrict__ Wb,
                                              float* __restrict__ out_f,
                                              unsigned short* __restrict__ out_b,
                                              int mode){
  __shared__ unsigned short As[2][128*32];
  __shared__ unsigned short Bs[2][128*32];
  int t0  = blockIdx.x * 128;
  int n0  = blockIdx.y * 128;
  int tid = threadIdx.x;
  int lane = tid & 63;
  int wv  = tid >> 6;
  int mw  = wv & 1, nw = wv >> 1;
  int m15 = lane & 15, quad = lane >> 4;

  int srow   = wv*32 + (lane >> 2);
  int schunk = ((lane & 3) ^ ((lane >> 3) & 3)) * 8;
  const unsigned short* gA = A  + (size_t)(t0 + srow)*DM + schunk;
  const unsigned short* gB = Wb + (size_t)(n0 + srow)*DM + schunk;
  unsigned short* asb0 = &As[0][(wv*32)*32];
  unsigned short* bsb0 = &Bs[0][(wv*32)*32];
  unsigned short* asb1 = &As[1][(wv*32)*32];
  unsigned short* bsb1 = &Bs[1][(wv*32)*32];

  async_cp16(gA,         asb0);
  async_cp16(gA + 16*DM, asb0 + 16*32);
  async_cp16(gB,         bsb0);
  async_cp16(gB + 16*DM, bsb0 + 16*32);

  f32x4 acc[4][4];
  #pragma unroll
  for (int rb=0;rb<4;rb++)
    #pragma unroll
    for (int cb=0;cb<4;cb++) acc[rb][cb] = (f32x4){0.f,0.f,0.f,0.f};

  int rdsw = (quad ^ ((m15 >> 1) & 3)) * 8;
  int cur = 0;
  for (int ks = 0; ks < 16; ks++){
    __syncthreads();
    if (ks < 15){
      const unsigned short* nA = gA + (ks+1)*32;
      const unsigned short* nB = gB + (ks+1)*32;
      unsigned short* na = cur ? asb0 : asb1;
      unsigned short* nb = cur ? bsb0 : bsb1;
      async_cp16(nA,         na);
      async_cp16(nA + 16*DM, na + 16*32);
      async_cp16(nB,         nb);
      async_cp16(nB + 16*DM, nb + 16*32);
    }
    bf16x8 af[4], bfr[4];
    #pragma unroll
    for (int rb=0;rb<4;rb++)
      af[rb] = *(const bf16x8*)&As[cur][(mw*64 + rb*16 + m15)*32 + rdsw];
    #pragma unroll
    for (int cb=0;cb<4;cb++)
      bfr[cb] = *(const bf16x8*)&Bs[cur][(nw*64 + cb*16 + m15)*32 + rdsw];
    #pragma unroll
    for (int rb=0;rb<4;rb++)
      #pragma unroll
      for (int cb=0;cb<4;cb++)
        acc[rb][cb] = __builtin_amdgcn_mfma_f32_16x16x32_bf16(af[rb], bfr[cb], acc[rb][cb], 0, 0, 0);
    cur ^= 1;
  }

  #pragma unroll
  for (int rb=0;rb<4;rb++){
    int tok0 = t0 + mw*64 + rb*16 + quad*4;
    int b    = tok0 >> 8;
    int tl0  = tok0 & 255;
    #pragma unroll
    for (int cb=0;cb<4;cb++){
      int nn = n0 + nw*64 + cb*16 + m15;
      f32x4 v = acc[rb][cb];
      if (mode == 0){
        if (nn < DM){
          *(f32x4*)(out_f + ((size_t)(b*DM + nn))*256 + tl0) = v;
        } else {
          uint2 z2 = { pk2(silu(v[0]), silu(v[1])), pk2(silu(v[2]), silu(v[3])) };
          *(uint2*)(out_b + ((size_t)(b*DM + (nn - DM)))*256 + tl0) = z2;
        }
      } else {
        #pragma unroll
        for (int r=0;r<4;r++) out_f[(size_t)(tok0+r)*DM + nn] = v[r];
      }
    }
  }
}

// -------- K3 (MFMA): conv4+silu -> bf16 A-tile; proj & dt via MFMA ----------
// 32 tokens/block (512 blocks). proj: M=32,N=64,K=512; dt: M=32,N=512,K=32.
__global__ __launch_bounds__(256) void k_xproj(const float* __restrict__ xiT,
                                               const float* __restrict__ cw,
                                               const float* __restrict__ cb,
                                               const unsigned short* __restrict__ xpwb,
                                               const unsigned short* __restrict__ dtwb,
                                               const float* __restrict__ dtb,
                                               float* __restrict__ dtT,
                                               float* __restrict__ Bc,
                                               float* __restrict__ Cc){
  __shared__ unsigned short xcb[32*520];      // conv+silu tile, bf16, stride 520
  __shared__ unsigned short Bst[2][64*32];    // xpw k-slab double buffer (XOR swizzled)
  __shared__ unsigned short pjA[32*40];       // dtr bf16, A-frag layout, +8 pad
  int t0  = blockIdx.x * 32;
  int b   = t0 >> 8;
  int tl0 = t0 & 255;
  int tid = threadIdx.x;
  int lane = tid & 63;
  int wv  = tid >> 6;
  int m15 = lane & 15, quad = lane >> 4;

  // ---- conv4 + silu -> xcb ----
  #pragma unroll
  for (int j=0;j<2;j++){
    int d = tid + 256*j;
    float4 cr = *(const float4*)(cw + d*4);
    float a0 = cb[d];
    const float* row = xiT + ((size_t)(b*DM + d))*256;
    float w[36];
    if (tl0 == 0){
      w[0]=w[1]=w[2]=w[3]=0.f;
      #pragma unroll
      for (int q2=0;q2<8;q2++){
        float4 v4 = *(const float4*)(row + q2*4);
        w[4+q2*4]=v4.x; w[5+q2*4]=v4.y; w[6+q2*4]=v4.z; w[7+q2*4]=v4.w;
      }
    } else {
      const float* p4 = row + tl0 - 4;
      #pragma unroll
      for (int q2=0;q2<9;q2++){
        float4 v4 = *(const float4*)(p4 + q2*4);
        w[q2*4]=v4.x; w[1+q2*4]=v4.y; w[2+q2*4]=v4.z; w[3+q2*4]=v4.w;
      }
    }
    #pragma unroll
    for (int t=0;t<32;t++){
      float a = a0 + w[t+1]*cr.x + w[t+2]*cr.y + w[t+3]*cr.z + w[t+4]*cr.w;
      xcb[t*520 + d] = f2bf(silu(a));
    }
  }

  // stage ks=0 of xpw (64 rows x 32 k), XOR chunk swizzle
  int srow = wv*16 + (lane >> 2);
  int sch  = ((lane & 3) ^ ((lane >> 3) & 3)) * 8;
  async_cp16(xpwb + srow*DM + sch, &Bst[0][(wv*16)*32]);
  __syncthreads();                 // xcb ready + stage0 drained

  // ---- proj MFMA: wave = (m-tile mt, nt-pair ntp) ----
  int mt = wv & 1, ntp = wv >> 1;
  f32x4 pacc[2];
  pacc[0] = (f32x4){0.f,0.f,0.f,0.f};
  pacc[1] = (f32x4){0.f,0.f,0.f,0.f};
  int rdsw = (quad ^ ((m15 >> 1) & 3)) * 8;
  int cur = 0;
  for (int ks=0; ks<16; ks++){
    if (ks < 15)
      async_cp16(xpwb + srow*DM + (ks+1)*32 + sch, &Bst[cur^1][(wv*16)*32]);
    bf16x8 af = *(const bf16x8*)&xcb[(mt*16 + m15)*520 + ks*32 + quad*8];
    #pragma unroll
    for (int j2=0;j2<2;j2++){
      int nt = ntp*2 + j2;
      bf16x8 bfr = *(const bf16x8*)&Bst[cur][(nt*16 + m15)*32 + rdsw];
      pacc[j2] = __builtin_amdgcn_mfma_f32_16x16x32_bf16(af, bfr, pacc[j2], 0, 0, 0);
    }
    cur ^= 1;
    __syncthreads();               // next slab staged; prev reads done
  }

  // dtr (cols 0..31) -> pjA (bf16, A-frag layout); cols 32..63 -> Bc/Cc
  if (ntp == 0){
    #pragma unroll
    for (int j2=0;j2<2;j2++){
      int col = j2*16 + m15;
      #pragma unroll
      for (int r=0;r<4;r++)
        pjA[(mt*16 + quad*4 + r)*40 + col] = f2bf(pacc[j2][r]);
    }
  } else {
    #pragma unroll
    for (int j2=0;j2<2;j2++){
      int c = j2*16 + m15;
      #pragma unroll
      for (int r=0;r<4;r++){
        int tt = t0 + mt*16 + quad*4 + r;
        float v = pacc[j2][r];
        if (c < 16) Bc[(size_t)tt*16 + c] = v;
        else        Cc[(size_t)tt*16 + (c-16)] = v;
      }
    }
  }
  __syncthreads();

  // ---- dt MFMA: M=32 (mt), N=512 split 2 waves x 16 n-tiles, K=32 ----
  bf16x8 adt = *(const bf16x8*)&pjA[(mt*16 + m15)*40 + quad*8];
  int nh = wv >> 1;
  #pragma unroll
  for (int j2=0;j2<16;j2++){
    int nn = (nh*16 + j2)*16 + m15;
    bf16x8 bfr = *(const bf16x8*)(dtwb + nn*32 + quad*8);
    f32x4 dacc = (f32x4){0.f,0.f,0.f,0.f};
    dacc = __builtin_amdgcn_mfma_f32_16x16x32_bf16(adt, bfr, dacc, 0, 0, 0);
    float bb = dtb[nn];
    f32x4 o;
    #pragma unroll
    for (int r=0;r<4;r++){
      float s = dacc[r] + bb;
      o[r] = (s > 20.f) ? s : log1pf(__expf(s));
    }
    *(f32x4*)(dtT + ((size_t)(b*DM + nn))*256 + tl0 + mt*16 + quad*4) = o;
  }
}

// ------ K4: scan, 4 lanes x 4 states per (b,d); T-layout float4 streams -----
__global__ __launch_bounds__(256) void k_scan(const float* __restrict__ dtT,
                                              const float* __restrict__ xiT,
                                              const unsigned short* __restrict__ zsT,
                                              const float* __restrict__ Bc,
                                              const float* __restrict__ Cc,
                                              const float* __restrict__ cw,
                                              const float* __restrict__ cb,
                                              const float* __restrict__ Alog,
                                              const float* __restrict__ Dpw,
                                              unsigned short* __restrict__ ya){
  int tid = threadIdx.x;
  int sl  = tid & 3;
  int q   = blockIdx.x*64 + (tid >> 2);
  int d   = q & 511;
  int b   = q >> 9;
  float4 Alr = *(const float4*)(Alog + d*16 + sl*4);
  float A0 = -__expf(Alr.x), A1 = -__expf(Alr.y);
  float A2 = -__expf(Alr.z), A3 = -__expf(Alr.w);
  float Dv = Dpw[d];
  float4 cr = *(const float4*)(cw + d*4);
  float cbv = cb[d];
  float h0=0.f, h1=0.f, h2=0.f, h3=0.f;
  float xm1=0.f, xm2=0.f, xm3=0.f;
  const float* dtp = dtT + (size_t)q*256;
  const float* xip = xiT + (size_t)q*256;
  const unsigned short* zsp = zsT + (size_t)q*256;
  unsigned short* yap = ya + (size_t)b*256*DM + d;
  const float* Bp = Bc + (size_t)b*4096 + sl*4;
  const float* Cp = Cc + (size_t)b*4096 + sl*4;
  #pragma unroll 2
  for (int t0=0; t0<256; t0+=4){
    float4 dt4 = *(const float4*)(dtp + t0);
    float4 xi4 = *(const float4*)(xip + t0);
    uint2  zz  = *(const uint2*)(zsp + t0);
    float xts[4] = {xi4.x, xi4.y, xi4.z, xi4.w};
    float dvs[4] = {dt4.x, dt4.y, dt4.z, dt4.w};
    float zsf[4] = { bfu((unsigned short)zz.x), bfu((unsigned short)(zz.x>>16)),
                     bfu((unsigned short)zz.y), bfu((unsigned short)(zz.y>>16)) };
    #pragma unroll
    for (int r=0;r<4;r++){
      float4 Bv = *(const float4*)(Bp + (t0+r)*16);
      float4 Cv = *(const float4*)(Cp + (t0+r)*16);
      float a  = cbv + xm3*cr.x + xm2*cr.y + xm1*cr.z + xts[r]*cr.w;
      float u  = silu(a);
      float dv = dvs[r];
      float du = dv*u;
      h0 = __expf(dv*A0)*h0 + du*Bv.x;
      h1 = __expf(dv*A1)*h1 + du*Bv.y;
      h2 = __expf(dv*A2)*h2 + du*Bv.z;
      h3 = __expf(dv*A3)*h3 + du*Bv.w;
      float yy = h0*Cv.x + h1*Cv.y + h2*Cv.z + h3*Cv.w;
      yy += __shfl_xor(yy, 1);
      yy += __shfl_xor(yy, 2);
      if (sl == 0) yap[(size_t)(t0+r)*DM] = f2bf((yy + u*Dv) * zsf[r]);
      xm3 = xm2; xm2 = xm1; xm1 = xts[r];
    }
  }
}

// ---------------- K5: out = LayerNorm(o + slots) (f32) ----------------------
__global__ __launch_bounds__(64) void k_fln(const float* __restrict__ o,
                                            const float* __restrict__ resid,
                                            const float* __restrict__ g,
                                            const float* __restrict__ b,
                                            float* __restrict__ out){
  int tok  = blockIdx.x;
  int lane = threadIdx.x;
  const float* row = o     + (size_t)tok*DM + lane*8;
  const float* rr  = resid + (size_t)tok*DM + lane*8;
  float4 r0 = *(const float4*)row;
  float4 r1 = *(const float4*)(row + 4);
  float4 s0 = *(const float4*)rr;
  float4 s1 = *(const float4*)(rr + 4);
  float v[8] = {r0.x+s0.x, r0.y+s0.y, r0.z+s0.z, r0.w+s0.w,
                r1.x+s1.x, r1.y+s1.y, r1.z+s1.z, r1.w+s1.w};
  float s = 0.f;
  #pragma unroll
  for (int i=0;i<8;i++) s += v[i];
  #pragma unroll
  for (int o2=32;o2;o2>>=1) s += __shfl_xor(s, o2, 64);
  float m = s * (1.0f/512.0f);
  float vs = 0.f;
  #pragma unroll
  for (int i=0;i<8;i++){ float d = v[i]-m; vs += d*d; }
  #pragma unroll
  for (int o2=32;o2;o2>>=1) vs += __shfl_xor(vs, o2, 64);
  float rs = rsqrtf(vs*(1.0f/512.0f) + 1e-5f);
  float4 g0 = *(const float4*)(g + lane*8);
  float4 g1 = *(const float4*)(g + lane*8 + 4);
  float4 b0 = *(const float4*)(b + lane*8);
  float4 b1 = *(const float4*)(b + lane*8 + 4);
  float gv[8] = {g0.x,g0.y,g0.z,g0.w, g1.x,g1.y,g1.z,g1.w};
  float bv[8] = {b0.x,b0.y,b0.z,b0.w, b1.x,b1.y,b1.z,b1.w};
  float o8[8];
  #pragma unroll
  for (int i=0;i<8;i++) o8[i] = (v[i]-m)*rs*gv[i] + bv[i];
  float4* op = (float4*)(out + (size_t)tok*DM + lane*8);
  op[0] = make_float4(o8[0],o8[1],o8[2],o8[3]);
  op[1] = make_float4(o8[4],o8[5],o8[6],o8[7]);
}

extern "C" void kernel_launch(void* const* d_in, const int* in_sizes, int n_in,
                              void* d_out, int out_size, void* d_ws, size_t ws_size,
                              hipStream_t stream) {
  const float* slots     = (const float*)d_in[0];
  const float* ln_g      = (const float*)d_in[1];
  const float* ln_b      = (const float*)d_in[2];
  const float* in_proj_w = (const float*)d_in[3];
  const float* conv_w    = (const float*)d_in[4];
  const float* conv_b    = (const float*)d_in[5];
  const float* x_proj_w  = (const float*)d_in[6];
  const float* dt_proj_w = (const float*)d_in[7];
  const float* dt_proj_b = (const float*)d_in[8];
  const float* A_log     = (const float*)d_in[9];
  const float* Dp        = (const float*)d_in[10];
  const float* out_projw = (const float*)d_in[11];
  const float* fln_g     = (const float*)d_in[12];
  const float* fln_b     = (const float*)d_in[13];
  float* out = (float*)d_out;

  const size_t MB = 1024*1024;
  char* base = (char*)d_ws;
  float*          xiT  = (float*)(base);                    // [0,32MB)
  unsigned short* xlnb = (unsigned short*)(base + 32*MB);   // [32,48MB)
  unsigned short* yab  = xlnb;                              // scan output (later)
  unsigned short* xpwb = xlnb;                              // 64KB, after gemm(in)
  unsigned short* dtwb = xlnb + 32768;                      // 32KB
  unsigned short* zsT  = (unsigned short*)(base + 48*MB);   // [48,64MB); head reused as WbO
  unsigned short* WbO  = zsT;
  float*          dto  = (float*)(base + 64*MB);            // [64,96MB): WbI -> dtT -> o
  unsigned short* WbI  = (unsigned short*)dto;
  float*          Bc   = (float*)(base + 96*MB);
  float*          Cc   = (float*)(base + 97*MB);

  k_ln   <<<NTOK,           64, 0, stream>>>(slots, ln_g, ln_b, xlnb);
  k_cvtw <<<256,           256, 0, stream>>>(in_proj_w, WbI);          // 1024x512
  k_gemm <<<dim3(128, 8),  256, 0, stream>>>(xlnb, WbI, xiT, zsT, 0);
  k_cvtw <<<16,            256, 0, stream>>>(x_proj_w, xpwb);          // 64x512
  k_cvtw <<<8,             256, 0, stream>>>(dt_proj_w, dtwb);         // 512x32
  k_xproj<<<NTOK/32,       256, 0, stream>>>(xiT, conv_w, conv_b, xpwb, dtwb, dt_proj_b,
                                             dto, Bc, Cc);
  k_scan <<<512,           256, 0, stream>>>(dto, xiT, zsT, Bc, Cc, conv_w, conv_b, A_log, Dp, yab);
  k_cvtw <<<128,           256, 0, stream>>>(out_projw, WbO);          // 512x512
  k_gemm <<<dim3(128, 4),  256, 0, stream>>>(yab, WbO, dto, (unsigned short*)0, 1);
  k_fln  <<<NTOK,           64, 0, stream>>>(dto, slots, fln_g, fln_b, out);
}

// Round 2
// 301.566 us; speedup vs baseline: 1.0590x; 1.0590x over previous
//
#include <hip/hip_runtime.h>
#include <hip/hip_bf16.h>

// SlotMamba: B=64, K=256, D_MODEL=512, D_INNER=512, D_STATE=16, D_CONV=4, DT_RANK=32
// NTOK = 16384. Inputs f32, output f32. All three GEMMs (in_proj, x_proj+dt_proj,
// out_proj) run as bf16 MFMA 16x16x32 with f32 accum.
// dt/xi/zs use T-layout: [(b*512+d)*256 + t].
//
// ws layout (MB = 2^20):                lifetime
//   xiT  [0,  32MB) f32 T-layout        gemm(in) -> xproj, scan
//   xlnb [32, 48MB) bf16 [t][d]         ln -> gemm(in); head reused as xpwb/dtwb (cvtw -> xproj);
//                                       whole region reused as yab: scan -> gemm(out)
//   zsT  [48, 64MB) bf16 T-layout       gemm(in) -> scan; head reused as WbO after scan
//   dtT/o[64, 96MB) f32                 head = WbI (cvtw -> gemm(in)); then dtT; then o [t][d]
//   Bc   [96, 97MB), Cc [97, 98MB)      xproj -> scan

#define NTOK 16384
#define DM   512

typedef __attribute__((ext_vector_type(8))) short bf16x8;
typedef __attribute__((ext_vector_type(4))) float f32x4;

__device__ __forceinline__ unsigned short f2bf(float f){
  unsigned int u = __float_as_uint(f);
  u = (u + 0x7fffu + ((u >> 16) & 1u)) >> 16;   // RNE
  return (unsigned short)u;
}
__device__ __forceinline__ float bfu(unsigned short p){ return __uint_as_float(((unsigned int)p) << 16); }
__device__ __forceinline__ unsigned int pk2(float a, float b){
  return (unsigned int)f2bf(a) | ((unsigned int)f2bf(b) << 16);
}
__device__ __forceinline__ float silu(float a){ return a / (1.f + __expf(-a)); }

// quad (4-lane) butterfly sum via DPP quad_perm -- no LDS pipe, pure VALU.
__device__ __forceinline__ float qsum(float x){
  x += __int_as_float(__builtin_amdgcn_mov_dpp(__float_as_int(x), 0xB1, 0xF, 0xF, true)); // xor 1
  x += __int_as_float(__builtin_amdgcn_mov_dpp(__float_as_int(x), 0x4E, 0xF, 0xF, true)); // xor 2
  return x;
}

// async 16B/lane global->LDS: lane l deposits at ldsbase + l*16 (wave-uniform base)
__device__ __forceinline__ void async_cp16(const unsigned short* g, unsigned short* l){
  __builtin_amdgcn_global_load_lds(
      (const __attribute__((address_space(1))) unsigned int*)g,
      (__attribute__((address_space(3))) unsigned int*)l, 16, 0, 0);
}

// ---------------- K0: f32 -> bf16 weight convert ----------------------------
__global__ __launch_bounds__(256) void k_cvtw(const float* __restrict__ W,
                                              unsigned short* __restrict__ Wb){
  int i = (blockIdx.x*256 + threadIdx.x)*8;
  float4 a = *(const float4*)(W+i);
  float4 b = *(const float4*)(W+i+4);
  uint4 st = { pk2(a.x,a.y), pk2(a.z,a.w), pk2(b.x,b.y), pk2(b.z,b.w) };
  *(uint4*)(Wb+i) = st;
}

// ---------------- K1: LayerNorm(slots) -> xlnb (bf16, [t][d]) ---------------
__global__ __launch_bounds__(64) void k_ln(const float* __restrict__ x,
                                           const float* __restrict__ g,
                                           const float* __restrict__ b,
                                           unsigned short* __restrict__ out){
  int tok  = blockIdx.x;
  int lane = threadIdx.x;
  const float* row = x + (size_t)tok*DM + lane*8;
  float4 r0 = *(const float4*)row;
  float4 r1 = *(const float4*)(row + 4);
  float v[8] = {r0.x,r0.y,r0.z,r0.w, r1.x,r1.y,r1.z,r1.w};
  float s = 0.f;
  #pragma unroll
  for (int i=0;i<8;i++) s += v[i];
  #pragma unroll
  for (int o=32;o;o>>=1) s += __shfl_xor(s, o, 64);
  float m = s * (1.0f/512.0f);
  float vs = 0.f;
  #pragma unroll
  for (int i=0;i<8;i++){ float d = v[i]-m; vs += d*d; }
  #pragma unroll
  for (int o=32;o;o>>=1) vs += __shfl_xor(vs, o, 64);
  float rs = rsqrtf(vs*(1.0f/512.0f) + 1e-5f);
  float4 g0 = *(const float4*)(g + lane*8);
  float4 g1 = *(const float4*)(g + lane*8 + 4);
  float4 b0 = *(const float4*)(b + lane*8);
  float4 b1 = *(const float4*)(b + lane*8 + 4);
  float gv[8] = {g0.x,g0.y,g0.z,g0.w, g1.x,g1.y,g1.z,g1.w};
  float bv[8] = {b0.x,b0.y,b0.z,b0.w, b1.x,b1.y,b1.z,b1.w};
  float o8[8];
  #pragma unroll
  for (int i=0;i<8;i++) o8[i] = (v[i]-m)*rs*gv[i] + bv[i];
  uint4 st = { pk2(o8[0],o8[1]), pk2(o8[2],o8[3]), pk2(o8[4],o8[5]), pk2(o8[6],o8[7]) };
  *(uint4*)(out + (size_t)tok*DM + lane*8) = st;
}

// ---------------- K2: 128x128-tile bf16-MFMA GEMM  C = A @ Wb^T -------------
__global__ __launch_bounds__(256) void k_gemm(const unsigned short* __restrict__ A,
                                              const unsigned short* __restrict__ Wb,
                                              float* __restrict__ out_f,
                                              unsigned short* __restrict__ out_b,
                                              int mode){
  __shared__ unsigned short As[2][128*32];
  __shared__ unsigned short Bs[2][128*32];
  int t0  = blockIdx.x * 128;
  int n0  = blockIdx.y * 128;
  int tid = threadIdx.x;
  int lane = tid & 63;
  int wv  = tid >> 6;
  int mw  = wv & 1, nw = wv >> 1;
  int m15 = lane & 15, quad = lane >> 4;

  int srow   = wv*32 + (lane >> 2);
  int schunk = ((lane & 3) ^ ((lane >> 3) & 3)) * 8;
  const unsigned short* gA = A  + (size_t)(t0 + srow)*DM + schunk;
  const unsigned short* gB = Wb + (size_t)(n0 + srow)*DM + schunk;
  unsigned short* asb0 = &As[0][(wv*32)*32];
  unsigned short* bsb0 = &Bs[0][(wv*32)*32];
  unsigned short* asb1 = &As[1][(wv*32)*32];
  unsigned short* bsb1 = &Bs[1][(wv*32)*32];

  async_cp16(gA,         asb0);
  async_cp16(gA + 16*DM, asb0 + 16*32);
  async_cp16(gB,         bsb0);
  async_cp16(gB + 16*DM, bsb0 + 16*32);

  f32x4 acc[4][4];
  #pragma unroll
  for (int rb=0;rb<4;rb++)
    #pragma unroll
    for (int cb=0;cb<4;cb++) acc[rb][cb] = (f32x4){0.f,0.f,0.f,0.f};

  int rdsw = (quad ^ ((m15 >> 1) & 3)) * 8;
  int cur = 0;
  for (int ks = 0; ks < 16; ks++){
    __syncthreads();
    if (ks < 15){
      const unsigned short* nA = gA + (ks+1)*32;
      const unsigned short* nB = gB + (ks+1)*32;
      unsigned short* na = cur ? asb0 : asb1;
      unsigned short* nb = cur ? bsb0 : bsb1;
      async_cp16(nA,         na);
      async_cp16(nA + 16*DM, na + 16*32);
      async_cp16(nB,         nb);
      async_cp16(nB + 16*DM, nb + 16*32);
    }
    bf16x8 af[4], bfr[4];
    #pragma unroll
    for (int rb=0;rb<4;rb++)
      af[rb] = *(const bf16x8*)&As[cur][(mw*64 + rb*16 + m15)*32 + rdsw];
    #pragma unroll
    for (int cb=0;cb<4;cb++)
      bfr[cb] = *(const bf16x8*)&Bs[cur][(nw*64 + cb*16 + m15)*32 + rdsw];
    #pragma unroll
    for (int rb=0;rb<4;rb++)
      #pragma unroll
      for (int cb=0;cb<4;cb++)
        acc[rb][cb] = __builtin_amdgcn_mfma_f32_16x16x32_bf16(af[rb], bfr[cb], acc[rb][cb], 0, 0, 0);
    cur ^= 1;
  }

  #pragma unroll
  for (int rb=0;rb<4;rb++){
    int tok0 = t0 + mw*64 + rb*16 + quad*4;
    int b    = tok0 >> 8;
    int tl0  = tok0 & 255;
    #pragma unroll
    for (int cb=0;cb<4;cb++){
      int nn = n0 + nw*64 + cb*16 + m15;
      f32x4 v = acc[rb][cb];
      if (mode == 0){
        if (nn < DM){
          *(f32x4*)(out_f + ((size_t)(b*DM + nn))*256 + tl0) = v;
        } else {
          uint2 z2 = { pk2(silu(v[0]), silu(v[1])), pk2(silu(v[2]), silu(v[3])) };
          *(uint2*)(out_b + ((size_t)(b*DM + (nn - DM)))*256 + tl0) = z2;
        }
      } else {
        #pragma unroll
        for (int r=0;r<4;r++) out_f[(size_t)(tok0+r)*DM + nn] = v[r];
      }
    }
  }
}

// -------- K3 (MFMA): conv4+silu -> bf16 A-tile; proj & dt via MFMA ----------
// 32 tokens/block (512 blocks). proj: M=32,N=64,K=512; dt: M=32,N=512,K=32.
__global__ __launch_bounds__(256) void k_xproj(const float* __restrict__ xiT,
                                               const float* __restrict__ cw,
                                               const float* __restrict__ cb,
                                               const unsigned short* __restrict__ xpwb,
                                               const unsigned short* __restrict__ dtwb,
                                               const float* __restrict__ dtb,
                                               float* __restrict__ dtT,
                                               float* __restrict__ Bc,
                                               float* __restrict__ Cc){
  __shared__ unsigned short xcb[32*520];      // conv+silu tile, bf16, stride 520
  __shared__ unsigned short Bst[2][64*32];    // xpw k-slab double buffer (XOR swizzled)
  __shared__ unsigned short pjA[32*40];       // dtr bf16, A-frag layout, +8 pad
  int t0  = blockIdx.x * 32;
  int b   = t0 >> 8;
  int tl0 = t0 & 255;
  int tid = threadIdx.x;
  int lane = tid & 63;
  int wv  = tid >> 6;
  int m15 = lane & 15, quad = lane >> 4;

  // ---- conv4 + silu -> xcb ----
  #pragma unroll
  for (int j=0;j<2;j++){
    int d = tid + 256*j;
    float4 cr = *(const float4*)(cw + d*4);
    float a0 = cb[d];
    const float* row = xiT + ((size_t)(b*DM + d))*256;
    float w[36];
    if (tl0 == 0){
      w[0]=w[1]=w[2]=w[3]=0.f;
      #pragma unroll
      for (int q2=0;q2<8;q2++){
        float4 v4 = *(const float4*)(row + q2*4);
        w[4+q2*4]=v4.x; w[5+q2*4]=v4.y; w[6+q2*4]=v4.z; w[7+q2*4]=v4.w;
      }
    } else {
      const float* p4 = row + tl0 - 4;
      #pragma unroll
      for (int q2=0;q2<9;q2++){
        float4 v4 = *(const float4*)(p4 + q2*4);
        w[q2*4]=v4.x; w[1+q2*4]=v4.y; w[2+q2*4]=v4.z; w[3+q2*4]=v4.w;
      }
    }
    #pragma unroll
    for (int t=0;t<32;t++){
      float a = a0 + w[t+1]*cr.x + w[t+2]*cr.y + w[t+3]*cr.z + w[t+4]*cr.w;
      xcb[t*520 + d] = f2bf(silu(a));
    }
  }

  // stage ks=0 of xpw (64 rows x 32 k), XOR chunk swizzle
  int srow = wv*16 + (lane >> 2);
  int sch  = ((lane & 3) ^ ((lane >> 3) & 3)) * 8;
  async_cp16(xpwb + srow*DM + sch, &Bst[0][(wv*16)*32]);
  __syncthreads();                 // xcb ready + stage0 drained

  // ---- proj MFMA: wave = (m-tile mt, nt-pair ntp) ----
  int mt = wv & 1, ntp = wv >> 1;
  f32x4 pacc[2];
  pacc[0] = (f32x4){0.f,0.f,0.f,0.f};
  pacc[1] = (f32x4){0.f,0.f,0.f,0.f};
  int rdsw = (quad ^ ((m15 >> 1) & 3)) * 8;
  int cur = 0;
  for (int ks=0; ks<16; ks++){
    if (ks < 15)
      async_cp16(xpwb + srow*DM + (ks+1)*32 + sch, &Bst[cur^1][(wv*16)*32]);
    bf16x8 af = *(const bf16x8*)&xcb[(mt*16 + m15)*520 + ks*32 + quad*8];
    #pragma unroll
    for (int j2=0;j2<2;j2++){
      int nt = ntp*2 + j2;
      bf16x8 bfr = *(const bf16x8*)&Bst[cur][(nt*16 + m15)*32 + rdsw];
      pacc[j2] = __builtin_amdgcn_mfma_f32_16x16x32_bf16(af, bfr, pacc[j2], 0, 0, 0);
    }
    cur ^= 1;
    __syncthreads();               // next slab staged; prev reads done
  }

  // dtr (cols 0..31) -> pjA (bf16, A-frag layout); cols 32..63 -> Bc/Cc
  if (ntp == 0){
    #pragma unroll
    for (int j2=0;j2<2;j2++){
      int col = j2*16 + m15;
      #pragma unroll
      for (int r=0;r<4;r++)
        pjA[(mt*16 + quad*4 + r)*40 + col] = f2bf(pacc[j2][r]);
    }
  } else {
    #pragma unroll
    for (int j2=0;j2<2;j2++){
      int c = j2*16 + m15;
      #pragma unroll
      for (int r=0;r<4;r++){
        int tt = t0 + mt*16 + quad*4 + r;
        float v = pacc[j2][r];
        if (c < 16) Bc[(size_t)tt*16 + c] = v;
        else        Cc[(size_t)tt*16 + (c-16)] = v;
      }
    }
  }
  __syncthreads();

  // ---- dt MFMA: M=32 (mt), N=512 split 2 waves x 16 n-tiles, K=32 ----
  bf16x8 adt = *(const bf16x8*)&pjA[(mt*16 + m15)*40 + quad*8];
  int nh = wv >> 1;
  #pragma unroll
  for (int j2=0;j2<16;j2++){
    int nn = (nh*16 + j2)*16 + m15;
    bf16x8 bfr = *(const bf16x8*)(dtwb + nn*32 + quad*8);
    f32x4 dacc = (f32x4){0.f,0.f,0.f,0.f};
    dacc = __builtin_amdgcn_mfma_f32_16x16x32_bf16(adt, bfr, dacc, 0, 0, 0);
    float bb = dtb[nn];
    f32x4 o;
    #pragma unroll
    for (int r=0;r<4;r++){
      float s = dacc[r] + bb;
      o[r] = (s > 20.f) ? s : log1pf(__expf(s));
    }
    *(f32x4*)(dtT + ((size_t)(b*DM + nn))*256 + tl0 + mt*16 + quad*4) = o;
  }
}

// ------ K4: scan, 4 lanes x 4 states per (b,d); T-layout float4 streams -----
// Latency-oriented rewrite: manual 2-deep register double-buffer on all five
// streams (dt, xi, zs, B, C), DPP quad-reduce (no LDS pipe), exp2-folded A,
// single exec-uniform 2B store per 4 tokens (lane sl stores token t0+sl).
#define SCAN_STEP(DV, XT, BV, CV, ZS, OUT) do {                                 \
    float a_ = fmaf((XT),cr.w, fmaf(xm1,cr.z, fmaf(xm2,cr.y, fmaf(xm3,cr.x, cbv)))); \
    float u_ = a_ / (1.f + __expf(-a_));                                        \
    float dv_ = (DV);                                                           \
    float du_ = dv_*u_;                                                         \
    h0 = fmaf(exp2f(dv_*A0), h0, du_*(BV).x);                                   \
    h1 = fmaf(exp2f(dv_*A1), h1, du_*(BV).y);                                   \
    h2 = fmaf(exp2f(dv_*A2), h2, du_*(BV).z);                                   \
    h3 = fmaf(exp2f(dv_*A3), h3, du_*(BV).w);                                   \
    float yy_ = fmaf(h3,(CV).w, fmaf(h2,(CV).z, fmaf(h1,(CV).y, h0*(CV).x)));   \
    yy_ = qsum(yy_);                                                            \
    OUT = fmaf(u_, Dv, yy_) * (ZS);                                             \
    xm3 = xm2; xm2 = xm1; xm1 = (XT);                                           \
  } while(0)

#define SCAN_LOAD(DT4, XI4, ZZ, B0,B1,B2,B3, C0,C1,C2,C3) do {                  \
    DT4 = *(const float4*)dtp;  XI4 = *(const float4*)xip;                      \
    ZZ  = *(const uint2*)zsp;                                                   \
    B0 = *(const float4*)(Bp);    B1 = *(const float4*)(Bp+16);                 \
    B2 = *(const float4*)(Bp+32); B3 = *(const float4*)(Bp+48);                 \
    C0 = *(const float4*)(Cp);    C1 = *(const float4*)(Cp+16);                 \
    C2 = *(const float4*)(Cp+32); C3 = *(const float4*)(Cp+48);                 \
    dtp += 4; xip += 4; zsp += 4; Bp += 64; Cp += 64;                           \
  } while(0)

#define SCAN_BODY(DT4, XI4, ZZ, B0,B1,B2,B3, C0,C1,C2,C3) do {                  \
    float zs0_ = __uint_as_float((ZZ).x << 16);                                 \
    float zs1_ = __uint_as_float((ZZ).x & 0xffff0000u);                         \
    float zs2_ = __uint_as_float((ZZ).y << 16);                                 \
    float zs3_ = __uint_as_float((ZZ).y & 0xffff0000u);                         \
    float o0_,o1_,o2_,o3_;                                                      \
    SCAN_STEP((DT4).x,(XI4).x,B0,C0,zs0_,o0_);                                  \
    SCAN_STEP((DT4).y,(XI4).y,B1,C1,zs1_,o1_);                                  \
    SCAN_STEP((DT4).z,(XI4).z,B2,C2,zs2_,o2_);                                  \
    SCAN_STEP((DT4).w,(XI4).w,B3,C3,zs3_,o3_);                                  \
    float osel_ = (sl==0)?o0_:(sl==1)?o1_:(sl==2)?o2_:o3_;                      \
    *yo = f2bf(osel_);                                                          \
    yo += 4*DM;                                                                 \
  } while(0)

__global__ __launch_bounds__(256) void k_scan(const float* __restrict__ dtT,
                                              const float* __restrict__ xiT,
                                              const unsigned short* __restrict__ zsT,
                                              const float* __restrict__ Bc,
                                              const float* __restrict__ Cc,
                                              const float* __restrict__ cw,
                                              const float* __restrict__ cb,
                                              const float* __restrict__ Alog,
                                              const float* __restrict__ Dpw,
                                              unsigned short* __restrict__ ya){
  int tid = threadIdx.x;
  int sl  = tid & 3;
  int q   = blockIdx.x*64 + (tid >> 2);
  int d   = q & 511;
  int b   = q >> 9;
  const float LOG2E = 1.44269504f;
  float4 Alr = *(const float4*)(Alog + d*16 + sl*4);
  float A0 = -__expf(Alr.x)*LOG2E, A1 = -__expf(Alr.y)*LOG2E;
  float A2 = -__expf(Alr.z)*LOG2E, A3 = -__expf(Alr.w)*LOG2E;
  float Dv = Dpw[d];
  float4 cr = *(const float4*)(cw + d*4);
  float cbv = cb[d];
  float h0=0.f, h1=0.f, h2=0.f, h3=0.f;
  float xm1=0.f, xm2=0.f, xm3=0.f;
  const float* dtp = dtT + (size_t)q*256;
  const float* xip = xiT + (size_t)q*256;
  const unsigned short* zsp = zsT + (size_t)q*256;
  unsigned short* yo = ya + (size_t)b*256*DM + d + sl*DM;
  const float* Bp = Bc + (size_t)b*4096 + sl*4;
  const float* Cp = Cc + (size_t)b*4096 + sl*4;

  // register double-buffer: set A = even iters, set B = odd iters
  float4 dtA, xiA, a0,a1,a2,a3, e0,e1,e2,e3; uint2 zzA;
  float4 dtB, xiB, f0,f1,f2,f3, g0,g1,g2,g3; uint2 zzB;

  SCAN_LOAD(dtA,xiA,zzA, a0,a1,a2,a3, e0,e1,e2,e3);          // data(0)
  for (int it = 0; it < 64; it += 2){
    SCAN_LOAD(dtB,xiB,zzB, f0,f1,f2,f3, g0,g1,g2,g3);        // data(it+1)
    SCAN_BODY(dtA,xiA,zzA, a0,a1,a2,a3, e0,e1,e2,e3);        // compute(it)
    if (it < 62)
      SCAN_LOAD(dtA,xiA,zzA, a0,a1,a2,a3, e0,e1,e2,e3);      // data(it+2)
    SCAN_BODY(dtB,xiB,zzB, f0,f1,f2,f3, g0,g1,g2,g3);        // compute(it+1)
  }
}

// ---------------- K5: out = LayerNorm(o + slots) (f32) ----------------------
__global__ __launch_bounds__(64) void k_fln(const float* __restrict__ o,
                                            const float* __restrict__ resid,
                                            const float* __restrict__ g,
                                            const float* __restrict__ b,
                                            float* __restrict__ out){
  int tok  = blockIdx.x;
  int lane = threadIdx.x;
  const float* row = o     + (size_t)tok*DM + lane*8;
  const float* rr  = resid + (size_t)tok*DM + lane*8;
  float4 r0 = *(const float4*)row;
  float4 r1 = *(const float4*)(row + 4);
  float4 s0 = *(const float4*)rr;
  float4 s1 = *(const float4*)(rr + 4);
  float v[8] = {r0.x+s0.x, r0.y+s0.y, r0.z+s0.z, r0.w+s0.w,
                r1.x+s1.x, r1.y+s1.y, r1.z+s1.z, r1.w+s1.w};
  float s = 0.f;
  #pragma unroll
  for (int i=0;i<8;i++) s += v[i];
  #pragma unroll
  for (int o2=32;o2;o2>>=1) s += __shfl_xor(s, o2, 64);
  float m = s * (1.0f/512.0f);
  float vs = 0.f;
  #pragma unroll
  for (int i=0;i<8;i++){ float d = v[i]-m; vs += d*d; }
  #pragma unroll
  for (int o2=32;o2;o2>>=1) vs += __shfl_xor(vs, o2, 64);
  float rs = rsqrtf(vs*(1.0f/512.0f) + 1e-5f);
  float4 g0 = *(const float4*)(g + lane*8);
  float4 g1 = *(const float4*)(g + lane*8 + 4);
  float4 b0 = *(const float4*)(b + lane*8);
  float4 b1 = *(const float4*)(b + lane*8 + 4);
  float gv[8] = {g0.x,g0.y,g0.z,g0.w, g1.x,g1.y,g1.z,g1.w};
  float bv[8] = {b0.x,b0.y,b0.z,b0.w, b1.x,b1.y,b1.z,b1.w};
  float o8[8];
  #pragma unroll
  for (int i=0;i<8;i++) o8[i] = (v[i]-m)*rs*gv[i] + bv[i];
  float4* op = (float4*)(out + (size_t)tok*DM + lane*8);
  op[0] = make_float4(o8[0],o8[1],o8[2],o8[3]);
  op[1] = make_float4(o8[4],o8[5],o8[6],o8[7]);
}

extern "C" void kernel_launch(void* const* d_in, const int* in_sizes, int n_in,
                              void* d_out, int out_size, void* d_ws, size_t ws_size,
                              hipStream_t stream) {
  const float* slots     = (const float*)d_in[0];
  const float* ln_g      = (const float*)d_in[1];
  const float* ln_b      = (const float*)d_in[2];
  const float* in_proj_w = (const float*)d_in[3];
  const float* conv_w    = (const float*)d_in[4];
  const float* conv_b    = (const float*)d_in[5];
  const float* x_proj_w  = (const float*)d_in[6];
  const float* dt_proj_w = (const float*)d_in[7];
  const float* dt_proj_b = (const float*)d_in[8];
  const float* A_log     = (const float*)d_in[9];
  const float* Dp        = (const float*)d_in[10];
  const float* out_projw = (const float*)d_in[11];
  const float* fln_g     = (const float*)d_in[12];
  const float* fln_b     = (const float*)d_in[13];
  float* out = (float*)d_out;

  const size_t MB = 1024*1024;
  char* base = (char*)d_ws;
  float*          xiT  = (float*)(base);                    // [0,32MB)
  unsigned short* xlnb = (unsigned short*)(base + 32*MB);   // [32,48MB)
  unsigned short* yab  = xlnb;                              // scan output (later)
  unsigned short* xpwb = xlnb;                              // 64KB, after gemm(in)
  unsigned short* dtwb = xlnb + 32768;                      // 32KB
  unsigned short* zsT  = (unsigned short*)(base + 48*MB);   // [48,64MB); head reused as WbO
  unsigned short* WbO  = zsT;
  float*          dto  = (float*)(base + 64*MB);            // [64,96MB): WbI -> dtT -> o
  unsigned short* WbI  = (unsigned short*)dto;
  float*          Bc   = (float*)(base + 96*MB);
  float*          Cc   = (float*)(base + 97*MB);

  k_ln   <<<NTOK,           64, 0, stream>>>(slots, ln_g, ln_b, xlnb);
  k_cvtw <<<256,           256, 0, stream>>>(in_proj_w, WbI);          // 1024x512
  k_gemm <<<dim3(128, 8),  256, 0, stream>>>(xlnb, WbI, xiT, zsT, 0);
  k_cvtw <<<16,            256, 0, stream>>>(x_proj_w, xpwb);          // 64x512
  k_cvtw <<<8,             256, 0, stream>>>(dt_proj_w, dtwb);         // 512x32
  k_xproj<<<NTOK/32,       256, 0, stream>>>(xiT, conv_w, conv_b, xpwb, dtwb, dt_proj_b,
                                             dto, Bc, Cc);
  k_scan <<<512,           256, 0, stream>>>(dto, xiT, zsT, Bc, Cc, conv_w, conv_b, A_log, Dp, yab);
  k_cvtw <<<128,           256, 0, stream>>>(out_projw, WbO);          // 512x512
  k_gemm <<<dim3(128, 4),  256, 0, stream>>>(yab, WbO, dto, (unsigned short*)0, 1);
  k_fln  <<<NTOK,           64, 0, stream>>>(dto, slots, fln_g, fln_b, out);
}

// Round 4
// 299.100 us; speedup vs baseline: 1.0677x; 1.0082x over previous
//
#include <hip/hip_runtime.h>
#include <hip/hip_bf16.h>

// SlotMamba: B=64, K=256, D_MODEL=512, D_INNER=512, D_STATE=16, D_CONV=4, DT_RANK=32
// NTOK = 16384. Inputs f32, output f32. All three GEMMs (in_proj, x_proj+dt_proj,
// out_proj) run as bf16 MFMA 16x16x32 with f32 accum.
// dt/xi/zs/xc use T-layout: [(b*512+d)*256 + t].
//
// ws layout (MB = 2^20):                lifetime
//   xiT  [0,  32MB) f32 T-layout        gemm(in) -> xproj (conv input)
//   xlnb [32, 48MB) bf16 [t][d]         ln -> gemm(in); head reused as xpwb/dtwb (cvtw -> xproj);
//                                       whole region reused as yab: scan -> gemm(out)
//   zsT  [48, 64MB) bf16 T-layout       gemm(in) -> scan; head reused as WbO after scan
//   dtTb [64, 80MB) bf16 T-layout       head = WbI (cvtw -> gemm(in)); then dt: xproj -> scan
//   xcT  [80, 96MB) bf16 T-layout       u = silu(conv): xproj -> scan
//   dto  [64, 96MB) f32 [t][d]          o: gemm(out) -> fln (after scan, reuses dtTb+xcT)
//   Bc   [96, 97MB), Cc [97, 98MB)      xproj -> scan

#define NTOK 16384
#define DM   512

typedef __attribute__((ext_vector_type(8))) short bf16x8;
typedef __attribute__((ext_vector_type(4))) float f32x4;

__device__ __forceinline__ unsigned short f2bf(float f){
  unsigned int u = __float_as_uint(f);
  u = (u + 0x7fffu + ((u >> 16) & 1u)) >> 16;   // RNE
  return (unsigned short)u;
}
__device__ __forceinline__ float bfu(unsigned short p){ return __uint_as_float(((unsigned int)p) << 16); }
__device__ __forceinline__ unsigned int pk2(float a, float b){
  return (unsigned int)f2bf(a) | ((unsigned int)f2bf(b) << 16);
}
__device__ __forceinline__ float silu(float a){ return a / (1.f + __expf(-a)); }

// quad (4-lane) butterfly sum via DPP quad_perm -- no LDS pipe, pure VALU.
__device__ __forceinline__ float qsum(float x){
  x += __int_as_float(__builtin_amdgcn_mov_dpp(__float_as_int(x), 0xB1, 0xF, 0xF, true)); // xor 1
  x += __int_as_float(__builtin_amdgcn_mov_dpp(__float_as_int(x), 0x4E, 0xF, 0xF, true)); // xor 2
  return x;
}

// async 16B/lane global->LDS: lane l deposits at ldsbase + l*16 (wave-uniform base)
__device__ __forceinline__ void async_cp16(const unsigned short* g, unsigned short* l){
  __builtin_amdgcn_global_load_lds(
      (const __attribute__((address_space(1))) unsigned int*)g,
      (__attribute__((address_space(3))) unsigned int*)l, 16, 0, 0);
}

// ---------------- K0: f32 -> bf16 weight convert ----------------------------
__global__ __launch_bounds__(256) void k_cvtw(const float* __restrict__ W,
                                              unsigned short* __restrict__ Wb){
  int i = (blockIdx.x*256 + threadIdx.x)*8;
  float4 a = *(const float4*)(W+i);
  float4 b = *(const float4*)(W+i+4);
  uint4 st = { pk2(a.x,a.y), pk2(a.z,a.w), pk2(b.x,b.y), pk2(b.z,b.w) };
  *(uint4*)(Wb+i) = st;
}

// ---------------- K1: LayerNorm(slots) -> xlnb (bf16, [t][d]) ---------------
__global__ __launch_bounds__(64) void k_ln(const float* __restrict__ x,
                                           const float* __restrict__ g,
                                           const float* __restrict__ b,
                                           unsigned short* __restrict__ out){
  int tok  = blockIdx.x;
  int lane = threadIdx.x;
  const float* row = x + (size_t)tok*DM + lane*8;
  float4 r0 = *(const float4*)row;
  float4 r1 = *(const float4*)(row + 4);
  float v[8] = {r0.x,r0.y,r0.z,r0.w, r1.x,r1.y,r1.z,r1.w};
  float s = 0.f;
  #pragma unroll
  for (int i=0;i<8;i++) s += v[i];
  #pragma unroll
  for (int o=32;o;o>>=1) s += __shfl_xor(s, o, 64);
  float m = s * (1.0f/512.0f);
  float vs = 0.f;
  #pragma unroll
  for (int i=0;i<8;i++){ float d = v[i]-m; vs += d*d; }
  #pragma unroll
  for (int o=32;o;o>>=1) vs += __shfl_xor(vs, o, 64);
  float rs = rsqrtf(vs*(1.0f/512.0f) + 1e-5f);
  float4 g0 = *(const float4*)(g + lane*8);
  float4 g1 = *(const float4*)(g + lane*8 + 4);
  float4 b0 = *(const float4*)(b + lane*8);
  float4 b1 = *(const float4*)(b + lane*8 + 4);
  float gv[8] = {g0.x,g0.y,g0.z,g0.w, g1.x,g1.y,g1.z,g1.w};
  float bv[8] = {b0.x,b0.y,b0.z,b0.w, b1.x,b1.y,b1.z,b1.w};
  float o8[8];
  #pragma unroll
  for (int i=0;i<8;i++) o8[i] = (v[i]-m)*rs*gv[i] + bv[i];
  uint4 st = { pk2(o8[0],o8[1]), pk2(o8[2],o8[3]), pk2(o8[4],o8[5]), pk2(o8[6],o8[7]) };
  *(uint4*)(out + (size_t)tok*DM + lane*8) = st;
}

// ---------------- K2: 128x128-tile bf16-MFMA GEMM  C = A @ Wb^T -------------
__global__ __launch_bounds__(256) void k_gemm(const unsigned short* __restrict__ A,
                                              const unsigned short* __restrict__ Wb,
                                              float* __restrict__ out_f,
                                              unsigned short* __restrict__ out_b,
                                              int mode){
  __shared__ unsigned short As[2][128*32];
  __shared__ unsigned short Bs[2][128*32];
  int t0  = blockIdx.x * 128;
  int n0  = blockIdx.y * 128;
  int tid = threadIdx.x;
  int lane = tid & 63;
  int wv  = tid >> 6;
  int mw  = wv & 1, nw = wv >> 1;
  int m15 = lane & 15, quad = lane >> 4;

  int srow   = wv*32 + (lane >> 2);
  int schunk = ((lane & 3) ^ ((lane >> 3) & 3)) * 8;
  const unsigned short* gA = A  + (size_t)(t0 + srow)*DM + schunk;
  const unsigned short* gB = Wb + (size_t)(n0 + srow)*DM + schunk;
  unsigned short* asb0 = &As[0][(wv*32)*32];
  unsigned short* bsb0 = &Bs[0][(wv*32)*32];
  unsigned short* asb1 = &As[1][(wv*32)*32];
  unsigned short* bsb1 = &Bs[1][(wv*32)*32];

  async_cp16(gA,         asb0);
  async_cp16(gA + 16*DM, asb0 + 16*32);
  async_cp16(gB,         bsb0);
  async_cp16(gB + 16*DM, bsb0 + 16*32);

  f32x4 acc[4][4];
  #pragma unroll
  for (int rb=0;rb<4;rb++)
    #pragma unroll
    for (int cb=0;cb<4;cb++) acc[rb][cb] = (f32x4){0.f,0.f,0.f,0.f};

  int rdsw = (quad ^ ((m15 >> 1) & 3)) * 8;
  int cur = 0;
  for (int ks = 0; ks < 16; ks++){
    __syncthreads();
    if (ks < 15){
      const unsigned short* nA = gA + (ks+1)*32;
      const unsigned short* nB = gB + (ks+1)*32;
      unsigned short* na = cur ? asb0 : asb1;
      unsigned short* nb = cur ? bsb0 : bsb1;
      async_cp16(nA,         na);
      async_cp16(nA + 16*DM, na + 16*32);
      async_cp16(nB,         nb);
      async_cp16(nB + 16*DM, nb + 16*32);
    }
    bf16x8 af[4], bfr[4];
    #pragma unroll
    for (int rb=0;rb<4;rb++)
      af[rb] = *(const bf16x8*)&As[cur][(mw*64 + rb*16 + m15)*32 + rdsw];
    #pragma unroll
    for (int cb=0;cb<4;cb++)
      bfr[cb] = *(const bf16x8*)&Bs[cur][(nw*64 + cb*16 + m15)*32 + rdsw];
    #pragma unroll
    for (int rb=0;rb<4;rb++)
      #pragma unroll
      for (int cb=0;cb<4;cb++)
        acc[rb][cb] = __builtin_amdgcn_mfma_f32_16x16x32_bf16(af[rb], bfr[cb], acc[rb][cb], 0, 0, 0);
    cur ^= 1;
  }

  #pragma unroll
  for (int rb=0;rb<4;rb++){
    int tok0 = t0 + mw*64 + rb*16 + quad*4;
    int b    = tok0 >> 8;
    int tl0  = tok0 & 255;
    #pragma unroll
    for (int cb=0;cb<4;cb++){
      int nn = n0 + nw*64 + cb*16 + m15;
      f32x4 v = acc[rb][cb];
      if (mode == 0){
        if (nn < DM){
          *(f32x4*)(out_f + ((size_t)(b*DM + nn))*256 + tl0) = v;
        } else {
          uint2 z2 = { pk2(silu(v[0]), silu(v[1])), pk2(silu(v[2]), silu(v[3])) };
          *(uint2*)(out_b + ((size_t)(b*DM + (nn - DM)))*256 + tl0) = z2;
        }
      } else {
        #pragma unroll
        for (int r=0;r<4;r++) out_f[(size_t)(tok0+r)*DM + nn] = v[r];
      }
    }
  }
}

// -------- K3 (MFMA): conv4+silu -> bf16 A-tile (LDS + global xcT);
//          proj & dt via MFMA; dt stored bf16 -----------------------------
// 32 tokens/block (512 blocks). proj: M=32,N=64,K=512; dt: M=32,N=512,K=32.
__global__ __launch_bounds__(256) void k_xproj(const float* __restrict__ xiT,
                                               const float* __restrict__ cw,
                                               const float* __restrict__ cb,
                                               const unsigned short* __restrict__ xpwb,
                                               const unsigned short* __restrict__ dtwb,
                                               const float* __restrict__ dtb,
                                               unsigned short* __restrict__ dtTb,
                                               unsigned short* __restrict__ xcT,
                                               float* __restrict__ Bc,
                                               float* __restrict__ Cc){
  __shared__ unsigned short xcb[32*520];      // conv+silu tile, bf16, stride 520
  __shared__ unsigned short Bst[2][64*32];    // xpw k-slab double buffer (XOR swizzled)
  __shared__ unsigned short pjA[32*40];       // dtr bf16, A-frag layout, +8 pad
  int t0  = blockIdx.x * 32;
  int b   = t0 >> 8;
  int tl0 = t0 & 255;
  int tid = threadIdx.x;
  int lane = tid & 63;
  int wv  = tid >> 6;
  int m15 = lane & 15, quad = lane >> 4;

  // ---- conv4 + silu -> xcb (LDS) + xcT (global bf16, T-layout) ----
  #pragma unroll
  for (int j=0;j<2;j++){
    int d = tid + 256*j;
    float4 cr = *(const float4*)(cw + d*4);
    float a0 = cb[d];
    const float* row = xiT + ((size_t)(b*DM + d))*256;
    float w[36];
    if (tl0 == 0){
      w[0]=w[1]=w[2]=w[3]=0.f;
      #pragma unroll
      for (int q2=0;q2<8;q2++){
        float4 v4 = *(const float4*)(row + q2*4);
        w[4+q2*4]=v4.x; w[5+q2*4]=v4.y; w[6+q2*4]=v4.z; w[7+q2*4]=v4.w;
      }
    } else {
      const float* p4 = row + tl0 - 4;
      #pragma unroll
      for (int q2=0;q2<9;q2++){
        float4 v4 = *(const float4*)(p4 + q2*4);
        w[q2*4]=v4.x; w[1+q2*4]=v4.y; w[2+q2*4]=v4.z; w[3+q2*4]=v4.w;
      }
    }
    unsigned short us[32];
    #pragma unroll
    for (int t=0;t<32;t++){
      float a = a0 + w[t+1]*cr.x + w[t+2]*cr.y + w[t+3]*cr.z + w[t+4]*cr.w;
      us[t] = f2bf(silu(a));
      xcb[t*520 + d] = us[t];
    }
    unsigned int pk[16];
    #pragma unroll
    for (int t=0;t<16;t++)
      pk[t] = (unsigned int)us[2*t] | ((unsigned int)us[2*t+1] << 16);
    uint4* xr = (uint4*)(xcT + ((size_t)(b*DM + d))*256 + tl0);
    xr[0] = *(uint4*)&pk[0];
    xr[1] = *(uint4*)&pk[4];
    xr[2] = *(uint4*)&pk[8];
    xr[3] = *(uint4*)&pk[12];
  }

  // stage ks=0 of xpw (64 rows x 32 k), XOR chunk swizzle
  int srow = wv*16 + (lane >> 2);
  int sch  = ((lane & 3) ^ ((lane >> 3) & 3)) * 8;
  async_cp16(xpwb + srow*DM + sch, &Bst[0][(wv*16)*32]);
  __syncthreads();                 // xcb ready + stage0 drained

  // ---- proj MFMA: wave = (m-tile mt, nt-pair ntp) ----
  int mt = wv & 1, ntp = wv >> 1;
  f32x4 pacc[2];
  pacc[0] = (f32x4){0.f,0.f,0.f,0.f};
  pacc[1] = (f32x4){0.f,0.f,0.f,0.f};
  int rdsw = (quad ^ ((m15 >> 1) & 3)) * 8;
  int cur = 0;
  for (int ks=0; ks<16; ks++){
    if (ks < 15)
      async_cp16(xpwb + srow*DM + (ks+1)*32 + sch, &Bst[cur^1][(wv*16)*32]);
    bf16x8 af = *(const bf16x8*)&xcb[(mt*16 + m15)*520 + ks*32 + quad*8];
    #pragma unroll
    for (int j2=0;j2<2;j2++){
      int nt = ntp*2 + j2;
      bf16x8 bfr = *(const bf16x8*)&Bst[cur][(nt*16 + m15)*32 + rdsw];
      pacc[j2] = __builtin_amdgcn_mfma_f32_16x16x32_bf16(af, bfr, pacc[j2], 0, 0, 0);
    }
    cur ^= 1;
    __syncthreads();               // next slab staged; prev reads done
  }

  // dtr (cols 0..31) -> pjA (bf16, A-frag layout); cols 32..63 -> Bc/Cc
  if (ntp == 0){
    #pragma unroll
    for (int j2=0;j2<2;j2++){
      int col = j2*16 + m15;
      #pragma unroll
      for (int r=0;r<4;r++)
        pjA[(mt*16 + quad*4 + r)*40 + col] = f2bf(pacc[j2][r]);
    }
  } else {
    #pragma unroll
    for (int j2=0;j2<2;j2++){
      int c = j2*16 + m15;
      #pragma unroll
      for (int r=0;r<4;r++){
        int tt = t0 + mt*16 + quad*4 + r;
        float v = pacc[j2][r];
        if (c < 16) Bc[(size_t)tt*16 + c] = v;
        else        Cc[(size_t)tt*16 + (c-16)] = v;
      }
    }
  }
  __syncthreads();

  // ---- dt MFMA: M=32 (mt), N=512 split 2 waves x 16 n-tiles, K=32 ----
  bf16x8 adt = *(const bf16x8*)&pjA[(mt*16 + m15)*40 + quad*8];
  int nh = wv >> 1;
  #pragma unroll
  for (int j2=0;j2<16;j2++){
    int nn = (nh*16 + j2)*16 + m15;
    bf16x8 bfr = *(const bf16x8*)(dtwb + nn*32 + quad*8);
    f32x4 dacc = (f32x4){0.f,0.f,0.f,0.f};
    dacc = __builtin_amdgcn_mfma_f32_16x16x32_bf16(adt, bfr, dacc, 0, 0, 0);
    float bb = dtb[nn];
    float o[4];
    #pragma unroll
    for (int r=0;r<4;r++){
      float s = dacc[r] + bb;
      o[r] = (s > 20.f) ? s : log1pf(__expf(s));
    }
    uint2 dst = { pk2(o[0],o[1]), pk2(o[2],o[3]) };
    *(uint2*)(dtTb + ((size_t)(b*DM + nn))*256 + tl0 + mt*16 + quad*4) = dst;
  }
}

// ------ K4: scan, 4 lanes x 4 states per (b,d); all streams bf16/f32 --------
// u = silu(conv) precomputed in k_xproj (xcT); dt precomputed bf16 (dtTb).
// Manual 2-deep register double-buffer, DPP quad-reduce, exp2-folded A.
#define SCAN_STEP(DV, UV, BV, CV, ZS, OUT) do {                                 \
    float dv_ = (DV);                                                           \
    float u_  = (UV);                                                           \
    float du_ = dv_*u_;                                                         \
    h0 = fmaf(exp2f(dv_*A0), h0, du_*(BV).x);                                   \
    h1 = fmaf(exp2f(dv_*A1), h1, du_*(BV).y);                                   \
    h2 = fmaf(exp2f(dv_*A2), h2, du_*(BV).z);                                   \
    h3 = fmaf(exp2f(dv_*A3), h3, du_*(BV).w);                                   \
    float yy_ = fmaf(h3,(CV).w, fmaf(h2,(CV).z, fmaf(h1,(CV).y, h0*(CV).x)));   \
    yy_ = qsum(yy_);                                                            \
    OUT = fmaf(u_, Dv, yy_) * (ZS);                                             \
  } while(0)

#define SCAN_LOAD(DD, UU, ZZ, B0,B1,B2,B3, C0,C1,C2,C3) do {                    \
    DD  = *(const uint2*)dtp;  UU = *(const uint2*)xup;                         \
    ZZ  = *(const uint2*)zsp;                                                   \
    B0 = *(const float4*)(Bp);    B1 = *(const float4*)(Bp+16);                 \
    B2 = *(const float4*)(Bp+32); B3 = *(const float4*)(Bp+48);                 \
    C0 = *(const float4*)(Cp);    C1 = *(const float4*)(Cp+16);                 \
    C2 = *(const float4*)(Cp+32); C3 = *(const float4*)(Cp+48);                 \
    dtp += 4; xup += 4; zsp += 4; Bp += 64; Cp += 64;                           \
  } while(0)

#define SCAN_BODY(DD, UU, ZZ, B0,B1,B2,B3, C0,C1,C2,C3) do {                    \
    float dv0_ = __uint_as_float((DD).x << 16);                                 \
    float dv1_ = __uint_as_float((DD).x & 0xffff0000u);                         \
    float dv2_ = __uint_as_float((DD).y << 16);                                 \
    float dv3_ = __uint_as_float((DD).y & 0xffff0000u);                         \
    float u0_ = __uint_as_float((UU).x << 16);                                  \
    float u1_ = __uint_as_float((UU).x & 0xffff0000u);                          \
    float u2_ = __uint_as_float((UU).y << 16);                                  \
    float u3_ = __uint_as_float((UU).y & 0xffff0000u);                          \
    float zs0_ = __uint_as_float((ZZ).x << 16);                                 \
    float zs1_ = __uint_as_float((ZZ).x & 0xffff0000u);                         \
    float zs2_ = __uint_as_float((ZZ).y << 16);                                 \
    float zs3_ = __uint_as_float((ZZ).y & 0xffff0000u);                         \
    float o0_,o1_,o2_,o3_;                                                      \
    SCAN_STEP(dv0_,u0_,B0,C0,zs0_,o0_);                                         \
    SCAN_STEP(dv1_,u1_,B1,C1,zs1_,o1_);                                         \
    SCAN_STEP(dv2_,u2_,B2,C2,zs2_,o2_);                                         \
    SCAN_STEP(dv3_,u3_,B3,C3,zs3_,o3_);                                         \
    float osel_ = (sl==0)?o0_:(sl==1)?o1_:(sl==2)?o2_:o3_;                      \
    *yo = f2bf(osel_);                                                          \
    yo += 4*DM;                                                                 \
  } while(0)

__global__ __launch_bounds__(256) void k_scan(const unsigned short* __restrict__ dtT,
                                              const unsigned short* __restrict__ xcT,
                                              const unsigned short* __restrict__ zsT,
                                              const float* __restrict__ Bc,
                                              const float* __restrict__ Cc,
                                              const float* __restrict__ Alog,
                                              const float* __restrict__ Dpw,
                                              unsigned short* __restrict__ ya){
  int tid = threadIdx.x;
  int sl  = tid & 3;
  int q   = blockIdx.x*64 + (tid >> 2);
  int d   = q & 511;
  int b   = q >> 9;
  const float LOG2E = 1.44269504f;
  float4 Alr = *(const float4*)(Alog + d*16 + sl*4);
  float A0 = -__expf(Alr.x)*LOG2E, A1 = -__expf(Alr.y)*LOG2E;
  float A2 = -__expf(Alr.z)*LOG2E, A3 = -__expf(Alr.w)*LOG2E;
  float Dv = Dpw[d];
  float h0=0.f, h1=0.f, h2=0.f, h3=0.f;
  const unsigned short* dtp = dtT + (size_t)q*256;
  const unsigned short* xup = xcT + (size_t)q*256;
  const unsigned short* zsp = zsT + (size_t)q*256;
  unsigned short* yo = ya + (size_t)b*256*DM + d + sl*DM;
  const float* Bp = Bc + (size_t)b*4096 + sl*4;
  const float* Cp = Cc + (size_t)b*4096 + sl*4;

  // register double-buffer: set A = even iters, set B = odd iters
  uint2 ddA, uuA, zzA; float4 a0,a1,a2,a3, e0,e1,e2,e3;
  uint2 ddB, uuB, zzB; float4 f0,f1,f2,f3, g0,g1,g2,g3;

  SCAN_LOAD(ddA,uuA,zzA, a0,a1,a2,a3, e0,e1,e2,e3);          // data(0)
  for (int it = 0; it < 64; it += 2){
    SCAN_LOAD(ddB,uuB,zzB, f0,f1,f2,f3, g0,g1,g2,g3);        // data(it+1)
    SCAN_BODY(ddA,uuA,zzA, a0,a1,a2,a3, e0,e1,e2,e3);        // compute(it)
    if (it < 62)
      SCAN_LOAD(ddA,uuA,zzA, a0,a1,a2,a3, e0,e1,e2,e3);      // data(it+2)
    SCAN_BODY(ddB,uuB,zzB, f0,f1,f2,f3, g0,g1,g2,g3);        // compute(it+1)
  }
}

// ---------------- K5: out = LayerNorm(o + slots) (f32) ----------------------
__global__ __launch_bounds__(64) void k_fln(const float* __restrict__ o,
                                            const float* __restrict__ resid,
                                            const float* __restrict__ g,
                                            const float* __restrict__ b,
                                            float* __restrict__ out){
  int tok  = blockIdx.x;
  int lane = threadIdx.x;
  const float* row = o     + (size_t)tok*DM + lane*8;
  const float* rr  = resid + (size_t)tok*DM + lane*8;
  float4 r0 = *(const float4*)row;
  float4 r1 = *(const float4*)(row + 4);
  float4 s0 = *(const float4*)rr;
  float4 s1 = *(const float4*)(rr + 4);
  float v[8] = {r0.x+s0.x, r0.y+s0.y, r0.z+s0.z, r0.w+s0.w,
                r1.x+s1.x, r1.y+s1.y, r1.z+s1.z, r1.w+s1.w};
  float s = 0.f;
  #pragma unroll
  for (int i=0;i<8;i++) s += v[i];
  #pragma unroll
  for (int o2=32;o2;o2>>=1) s += __shfl_xor(s, o2, 64);
  float m = s * (1.0f/512.0f);
  float vs = 0.f;
  #pragma unroll
  for (int i=0;i<8;i++){ float d = v[i]-m; vs += d*d; }
  #pragma unroll
  for (int o2=32;o2;o2>>=1) vs += __shfl_xor(vs, o2, 64);
  float rs = rsqrtf(vs*(1.0f/512.0f) + 1e-5f);
  float4 g0 = *(const float4*)(g + lane*8);
  float4 g1 = *(const float4*)(g + lane*8 + 4);
  float4 b0 = *(const float4*)(b + lane*8);
  float4 b1 = *(const float4*)(b + lane*8 + 4);
  float gv[8] = {g0.x,g0.y,g0.z,g0.w, g1.x,g1.y,g1.z,g1.w};
  float bv[8] = {b0.x,b0.y,b0.z,b0.w, b1.x,b1.y,b1.z,b1.w};
  float o8[8];
  #pragma unroll
  for (int i=0;i<8;i++) o8[i] = (v[i]-m)*rs*gv[i] + bv[i];
  float4* op = (float4*)(out + (size_t)tok*DM + lane*8);
  op[0] = make_float4(o8[0],o8[1],o8[2],o8[3]);
  op[1] = make_float4(o8[4],o8[5],o8[6],o8[7]);
}

extern "C" void kernel_launch(void* const* d_in, const int* in_sizes, int n_in,
                              void* d_out, int out_size, void* d_ws, size_t ws_size,
                              hipStream_t stream) {
  const float* slots     = (const float*)d_in[0];
  const float* ln_g      = (const float*)d_in[1];
  const float* ln_b      = (const float*)d_in[2];
  const float* in_proj_w = (const float*)d_in[3];
  const float* conv_w    = (const float*)d_in[4];
  const float* conv_b    = (const float*)d_in[5];
  const float* x_proj_w  = (const float*)d_in[6];
  const float* dt_proj_w = (const float*)d_in[7];
  const float* dt_proj_b = (const float*)d_in[8];
  const float* A_log     = (const float*)d_in[9];
  const float* Dp        = (const float*)d_in[10];
  const float* out_projw = (const float*)d_in[11];
  const float* fln_g     = (const float*)d_in[12];
  const float* fln_b     = (const float*)d_in[13];
  float* out = (float*)d_out;

  const size_t MB = 1024*1024;
  char* base = (char*)d_ws;
  float*          xiT  = (float*)(base);                    // [0,32MB)
  unsigned short* xlnb = (unsigned short*)(base + 32*MB);   // [32,48MB)
  unsigned short* yab  = xlnb;                              // scan output (later)
  unsigned short* xpwb = xlnb;                              // 64KB, after gemm(in)
  unsigned short* dtwb = xlnb + 32768;                      // 32KB
  unsigned short* zsT  = (unsigned short*)(base + 48*MB);   // [48,64MB); head reused as WbO
  unsigned short* WbO  = zsT;
  unsigned short* dtTb = (unsigned short*)(base + 64*MB);   // [64,80MB) bf16 dt
  unsigned short* xcT  = (unsigned short*)(base + 80*MB);   // [80,96MB) bf16 u
  float*          dto  = (float*)(base + 64*MB);            // [64,96MB) o (after scan)
  unsigned short* WbI  = (unsigned short*)dto;              // 1MB head, before xproj
  float*          Bc   = (float*)(base + 96*MB);
  float*          Cc   = (float*)(base + 97*MB);

  k_ln   <<<NTOK,           64, 0, stream>>>(slots, ln_g, ln_b, xlnb);
  k_cvtw <<<256,           256, 0, stream>>>(in_proj_w, WbI);          // 1024x512
  k_gemm <<<dim3(128, 8),  256, 0, stream>>>(xlnb, WbI, xiT, zsT, 0);
  k_cvtw <<<16,            256, 0, stream>>>(x_proj_w, xpwb);          // 64x512
  k_cvtw <<<8,             256, 0, stream>>>(dt_proj_w, dtwb);         // 512x32
  k_xproj<<<NTOK/32,       256, 0, stream>>>(xiT, conv_w, conv_b, xpwb, dtwb, dt_proj_b,
                                             dtTb, xcT, Bc, Cc);
  k_scan <<<512,           256, 0, stream>>>(dtTb, xcT, zsT, Bc, Cc, A_log, Dp, yab);
  k_cvtw <<<128,           256, 0, stream>>>(out_projw, WbO);          // 512x512
  k_gemm <<<dim3(128, 4),  256, 0, stream>>>(yab, WbO, dto, (unsigned short*)0, 1);
  k_fln  <<<NTOK,           64, 0, stream>>>(dto, slots, fln_g, fln_b, out);
}